// Round 8
// baseline (129.149 us; speedup 1.0000x reference)
//
#include <hip/hip_runtime.h>
#include <cstdint>

#define D_MODEL 128
#define D_EMB   64
#define MAXLEN  32
#define NB      2
#define NMSA    4
#define LL      768
#define JCHUNK  256   // j's per tile (128KB contiguous per tile)
#define NCHUNK  (LL / JCHUNK)                 // 3 tiles per bi
#define NREL    (2 * MAXLEN - 1)
#define NBLOCKS 256
#define NTILES  (NB * LL * NCHUNK)            // 4608
#define TILES_PER_BLOCK (NTILES / NBLOCKS)    // 18, exact

typedef float f32x4 __attribute__((ext_vector_type(4)));

// Fused prep:
//  blocks 0 .. NB*LL-1 : P[bi][d] = sum_k e[bi,k] * W_proj[k][d]
//                        Q[bi][d] = sum_k e[bi,k] * W_proj[64+k][d]
//  block  NB*LL        : R[r][d]  = W_pos[r][d] + b_pos[d] + b_proj[d]
__global__ void prep_kernel(const int* __restrict__ msa_tokens,
                            const float* __restrict__ emb,
                            const float* __restrict__ W_proj,
                            const float* __restrict__ b_proj,
                            const float* __restrict__ W_pos,
                            const float* __restrict__ b_pos,
                            float* __restrict__ P, float* __restrict__ Q,
                            float* __restrict__ R) {
    int bi = blockIdx.x;
    int d  = threadIdx.x;           // 0 .. 127
    if (bi == NB * LL) {
        float bias = b_pos[d] + b_proj[d];
        #pragma unroll
        for (int r = 0; r < NREL; ++r) {
            R[r * D_MODEL + d] = W_pos[r * D_MODEL + d] + bias;
        }
        return;
    }
    int b = bi / LL;
    int i = bi - b * LL;
    __shared__ float e[D_EMB];
    int tok = msa_tokens[(b * NMSA + 0) * LL + i];
    if (d < D_EMB) {
        e[d] = (tok != 0) ? emb[tok * D_EMB + d] : 0.0f;
    }
    __syncthreads();
    float p = 0.f, q = 0.f;
    #pragma unroll
    for (int k = 0; k < D_EMB; ++k) {
        float ek = e[k];
        p = fmaf(ek, W_proj[k * D_MODEL + d], p);
        q = fmaf(ek, W_proj[(D_EMB + k) * D_MODEL + d], q);
    }
    P[bi * D_MODEL + d] = p;
    Q[bi * D_MODEL + d] = q;
}

// out[b,i,j,d] = P[b,i,d] + Q[b,j,d] + R[clip(i-j,-31,31)+31, d]
// Persistent: 256 blocks (1/CU via 100KB ballast), each owns 18 CONTIGUOUS
// tiles -> one 2.25MB linear NT-store stream per CU, zero dispatch churn,
// perfect balance. R6/R7 established: fewer+longer streams = faster.
__global__ __launch_bounds__(256) void fill_kernel(
        const float* __restrict__ P, const float* __restrict__ Q,
        const float* __restrict__ R, float* __restrict__ out) {
    volatile __shared__ float ballast[25600];   // 100 KB -> 1 block/CU
    ballast[threadIdx.x] = 0.0f;

    int t  = threadIdx.x;
    int d4 = t & 31;                // which float4 of the 128-dim channel
    int jo = t >> 5;                // 0..7

    const f32x4* P4 = reinterpret_cast<const f32x4*>(P);
    const f32x4* Q4 = reinterpret_cast<const f32x4*>(Q);
    const f32x4* R4 = reinterpret_cast<const f32x4*>(R);
    f32x4* o4 = reinterpret_cast<f32x4*>(out);

    int tile0 = blockIdx.x * TILES_PER_BLOCK;
    for (int tt = 0; tt < TILES_PER_BLOCK; ++tt) {
        int tile  = tile0 + tt;
        int bi    = tile / NCHUNK;
        int ch    = tile - bi * NCHUNK;
        int isb   = bi >= LL;
        int i     = bi - (isb ? LL : 0);
        int jbase = ch * JCHUNK;

        const f32x4* Qb = Q4 + (size_t)(isb ? LL : 0) * 32;
        f32x4 p = P4[(size_t)bi * 32 + d4];
        f32x4* orow = o4 + ((size_t)bi * LL + jbase) * 32;

        #pragma unroll
        for (int jj = 0; jj < JCHUNK; jj += 8) {
            int j = jbase + jj + jo;
            int rel = i - j;
            rel = rel > (MAXLEN - 1) ? (MAXLEN - 1) : rel;
            rel = rel < -(MAXLEN - 1) ? -(MAXLEN - 1) : rel;
            rel += MAXLEN - 1;

            f32x4 q = Qb[(size_t)j * 32 + d4];
            f32x4 r = R4[rel * 32 + d4];
            f32x4 o = p + q + r;
            __builtin_nontemporal_store(o, &orow[(size_t)(jj + jo) * 32 + d4]);
        }
    }
}

extern "C" void kernel_launch(void* const* d_in, const int* in_sizes, int n_in,
                              void* d_out, int out_size, void* d_ws, size_t ws_size,
                              hipStream_t stream) {
    const int*   msa    = (const int*)d_in[0];
    const float* emb    = (const float*)d_in[1];
    const float* W_proj = (const float*)d_in[2];
    const float* b_proj = (const float*)d_in[3];
    const float* W_pos  = (const float*)d_in[4];
    const float* b_pos  = (const float*)d_in[5];
    float* out = (float*)d_out;

    float* P = (float*)d_ws;                       // NB*LL*128 floats
    float* Q = P + (size_t)NB * LL * D_MODEL;      // NB*LL*128 floats
    float* R = Q + (size_t)NB * LL * D_MODEL;      // NREL*128 floats

    prep_kernel<<<NB * LL + 1, D_MODEL, 0, stream>>>(msa, emb, W_proj, b_proj,
                                                     W_pos, b_pos, P, Q, R);
    fill_kernel<<<NBLOCKS, 256, 0, stream>>>(P, Q, R, out);
}

// Round 9
// 124.559 us; speedup vs baseline: 1.0369x; 1.0369x over previous
//
#include <hip/hip_runtime.h>
#include <cstdint>

#define D_MODEL 128
#define D_EMB   64
#define MAXLEN  32
#define NB      2
#define NMSA    4
#define LL      768
#define NREL    (2 * MAXLEN - 1)

#define NBLOCKS   256
#define TILE_ROWS 64                          // 32KB per tile
#define CH_PER_BI (LL / TILE_ROWS)            // 12
#define NTILES    (NB * LL * CH_PER_BI)       // 18432
#define NSTEPS    (NTILES / NBLOCKS)          // 72, exact

typedef float f32x4 __attribute__((ext_vector_type(4)));

// Fused prep:
//  blocks 0 .. NB*LL-1 : P[bi][d] = sum_k e[bi,k] * W_proj[k][d]
//                        Q[bi][d] = sum_k e[bi,k] * W_proj[64+k][d]
//  block  NB*LL        : R[r][d]  = W_pos[r][d] + b_pos[d] + b_proj[d]
__global__ void prep_kernel(const int* __restrict__ msa_tokens,
                            const float* __restrict__ emb,
                            const float* __restrict__ W_proj,
                            const float* __restrict__ b_proj,
                            const float* __restrict__ W_pos,
                            const float* __restrict__ b_pos,
                            float* __restrict__ P, float* __restrict__ Q,
                            float* __restrict__ R) {
    int bi = blockIdx.x;
    int d  = threadIdx.x;           // 0 .. 127
    if (bi == NB * LL) {
        float bias = b_pos[d] + b_proj[d];
        #pragma unroll
        for (int r = 0; r < NREL; ++r) {
            R[r * D_MODEL + d] = W_pos[r * D_MODEL + d] + bias;
        }
        return;
    }
    int b = bi / LL;
    int i = bi - b * LL;
    __shared__ float e[D_EMB];
    int tok = msa_tokens[(b * NMSA + 0) * LL + i];
    if (d < D_EMB) {
        e[d] = (tok != 0) ? emb[tok * D_EMB + d] : 0.0f;
    }
    __syncthreads();
    float p = 0.f, q = 0.f;
    #pragma unroll
    for (int k = 0; k < D_EMB; ++k) {
        float ek = e[k];
        p = fmaf(ek, W_proj[k * D_MODEL + d], p);
        q = fmaf(ek, W_proj[(D_EMB + k) * D_MODEL + d], q);
    }
    P[bi * D_MODEL + d] = p;
    Q[bi * D_MODEL + d] = q;
}

// out[b,i,j,d] = P[b,i,d] + Q[b,j,d] + R[clip(i-j,-31,31)+31, d]
// Persistent 256 blocks (1/CU via ballast), INTERLEAVED tiles:
// tile = s*256 + blockIdx.x, tile = 32KB. At any instant the device's
// stores form one dense ~8MB window marching linearly through the output
// (fillBuffer's regime). R8 proved dispersion hurts; R6/R7 proved fewer
// streams help; this maximizes window density.
__global__ __launch_bounds__(256) void fill_kernel(
        const float* __restrict__ P, const float* __restrict__ Q,
        const float* __restrict__ R, float* __restrict__ out) {
    volatile __shared__ float ballast[25600];   // 100 KB -> 1 block/CU
    ballast[threadIdx.x] = 0.0f;

    int t  = threadIdx.x;
    int d4 = t & 31;                // which float4 of the 128-dim channel
    int jo = t >> 5;                // 0..7

    const f32x4* P4 = reinterpret_cast<const f32x4*>(P);
    const f32x4* Q4 = reinterpret_cast<const f32x4*>(Q);
    const f32x4* R4 = reinterpret_cast<const f32x4*>(R);
    f32x4* o4 = reinterpret_cast<f32x4*>(out);

    for (int s = 0; s < NSTEPS; ++s) {
        int tau   = s * NBLOCKS + (int)blockIdx.x;
        int bi    = tau / CH_PER_BI;            // magic-mul division
        int ch    = tau - bi * CH_PER_BI;
        int isb   = bi >= LL;
        int i     = bi - (isb ? LL : 0);
        int jbase = ch * TILE_ROWS;

        const f32x4* Qb = Q4 + (size_t)(isb ? LL : 0) * 32;
        f32x4 p = P4[(size_t)bi * 32 + d4];
        f32x4* orow = o4 + ((size_t)bi * LL + jbase) * 32;

        #pragma unroll
        for (int jj = 0; jj < TILE_ROWS; jj += 8) {
            int j = jbase + jj + jo;
            int rel = i - j;
            rel = rel > (MAXLEN - 1) ? (MAXLEN - 1) : rel;
            rel = rel < -(MAXLEN - 1) ? -(MAXLEN - 1) : rel;
            rel += MAXLEN - 1;

            f32x4 q = Qb[(size_t)j * 32 + d4];
            f32x4 r = R4[rel * 32 + d4];
            f32x4 o = p + q + r;
            __builtin_nontemporal_store(o, &orow[(size_t)(jj + jo) * 32 + d4]);
        }
    }
}

extern "C" void kernel_launch(void* const* d_in, const int* in_sizes, int n_in,
                              void* d_out, int out_size, void* d_ws, size_t ws_size,
                              hipStream_t stream) {
    const int*   msa    = (const int*)d_in[0];
    const float* emb    = (const float*)d_in[1];
    const float* W_proj = (const float*)d_in[2];
    const float* b_proj = (const float*)d_in[3];
    const float* W_pos  = (const float*)d_in[4];
    const float* b_pos  = (const float*)d_in[5];
    float* out = (float*)d_out;

    float* P = (float*)d_ws;                       // NB*LL*128 floats
    float* Q = P + (size_t)NB * LL * D_MODEL;      // NB*LL*128 floats
    float* R = Q + (size_t)NB * LL * D_MODEL;      // NREL*128 floats

    prep_kernel<<<NB * LL + 1, D_MODEL, 0, stream>>>(msa, emb, W_proj, b_proj,
                                                     W_pos, b_pos, P, Q, R);
    fill_kernel<<<NBLOCKS, 256, 0, stream>>>(P, Q, R, out);
}

// Round 10
// 116.290 us; speedup vs baseline: 1.1106x; 1.0711x over previous
//
#include <hip/hip_runtime.h>
#include <cstdint>

#define D_MODEL 128
#define D_EMB   64
#define MAXLEN  32
#define NB      2
#define NMSA    4
#define LL      768
#define JCHUNK  256   // j's per block (128KB contiguous stream per block)
#define NREL    (2 * MAXLEN - 1)

typedef float f32x4 __attribute__((ext_vector_type(4)));

// Fused prep:
//  blocks 0 .. NB*LL-1 : P[bi][d] = sum_k e[bi,k] * W_proj[k][d]
//                        Q[bi][d] = sum_k e[bi,k] * W_proj[64+k][d]
//  block  NB*LL        : R[r][d]  = W_pos[r][d] + b_pos[d] + b_proj[d]
__global__ void prep_kernel(const int* __restrict__ msa_tokens,
                            const float* __restrict__ emb,
                            const float* __restrict__ W_proj,
                            const float* __restrict__ b_proj,
                            const float* __restrict__ W_pos,
                            const float* __restrict__ b_pos,
                            float* __restrict__ P, float* __restrict__ Q,
                            float* __restrict__ R) {
    int bi = blockIdx.x;
    int d  = threadIdx.x;           // 0 .. 127
    if (bi == NB * LL) {
        float bias = b_pos[d] + b_proj[d];
        #pragma unroll
        for (int r = 0; r < NREL; ++r) {
            R[r * D_MODEL + d] = W_pos[r * D_MODEL + d] + bias;
        }
        return;
    }
    int b = bi / LL;
    int i = bi - b * LL;
    __shared__ float e[D_EMB];
    int tok = msa_tokens[(b * NMSA + 0) * LL + i];
    if (d < D_EMB) {
        e[d] = (tok != 0) ? emb[tok * D_EMB + d] : 0.0f;
    }
    __syncthreads();
    float p = 0.f, q = 0.f;
    #pragma unroll
    for (int k = 0; k < D_EMB; ++k) {
        float ek = e[k];
        p = fmaf(ek, W_proj[k * D_MODEL + d], p);
        q = fmaf(ek, W_proj[(D_EMB + k) * D_MODEL + d], q);
    }
    P[bi * D_MODEL + d] = p;
    Q[bi * D_MODEL + d] = q;
}

// out[b,i,j,d] = P[b,i,d] + Q[b,j,d] + R[clip(i-j,-31,31)+31, d]
// R7 structure (best: 121.2us): 100KB ballast -> 1 block/CU, 128KB stream
// per block, hardware-dispatch marching window. A/B this round: PLAIN
// stores through L2 write-back (fillBuffer's mode, 6.7 TB/s at this same
// low occupancy) instead of NT — write-back evicts in large address-sorted
// bursts; NT sends individual no-allocate lines.
__global__ __launch_bounds__(256) void fill_kernel(
        const float* __restrict__ P, const float* __restrict__ Q,
        const float* __restrict__ R, float* __restrict__ out) {
    volatile __shared__ float ballast[25600];   // 100 KB -> 1 block/CU
    ballast[threadIdx.x] = 0.0f;

    int bi    = blockIdx.y;         // b*LL + i
    int b     = bi / LL;
    int i     = bi - b * LL;
    int jbase = blockIdx.x * JCHUNK;
    int t     = threadIdx.x;
    int d4    = t & 31;             // which float4 of the 128-dim channel
    int jo    = t >> 5;             // 0..7

    const f32x4* P4 = reinterpret_cast<const f32x4*>(P);
    const f32x4* Qb = reinterpret_cast<const f32x4*>(Q + (size_t)b * LL * D_MODEL);
    const f32x4* R4 = reinterpret_cast<const f32x4*>(R);
    f32x4* orow = reinterpret_cast<f32x4*>(out + ((size_t)bi * LL + jbase) * D_MODEL);

    f32x4 p = P4[(size_t)bi * 32 + d4];

    #pragma unroll
    for (int jj = 0; jj < JCHUNK; jj += 8) {
        int j = jbase + jj + jo;
        int rel = i - j;
        rel = rel > (MAXLEN - 1) ? (MAXLEN - 1) : rel;
        rel = rel < -(MAXLEN - 1) ? -(MAXLEN - 1) : rel;
        rel += MAXLEN - 1;

        f32x4 q = Qb[(size_t)j * 32 + d4];
        f32x4 r = R4[rel * 32 + d4];
        orow[(size_t)(jj + jo) * 32 + d4] = p + q + r;
    }
}

extern "C" void kernel_launch(void* const* d_in, const int* in_sizes, int n_in,
                              void* d_out, int out_size, void* d_ws, size_t ws_size,
                              hipStream_t stream) {
    const int*   msa    = (const int*)d_in[0];
    const float* emb    = (const float*)d_in[1];
    const float* W_proj = (const float*)d_in[2];
    const float* b_proj = (const float*)d_in[3];
    const float* W_pos  = (const float*)d_in[4];
    const float* b_pos  = (const float*)d_in[5];
    float* out = (float*)d_out;

    float* P = (float*)d_ws;                       // NB*LL*128 floats
    float* Q = P + (size_t)NB * LL * D_MODEL;      // NB*LL*128 floats
    float* R = Q + (size_t)NB * LL * D_MODEL;      // NREL*128 floats

    prep_kernel<<<NB * LL + 1, D_MODEL, 0, stream>>>(msa, emb, W_proj, b_proj,
                                                     W_pos, b_pos, P, Q, R);
    fill_kernel<<<dim3(LL / JCHUNK, NB * LL), 256, 0, stream>>>(P, Q, R, out);
}

// Round 11
// 112.960 us; speedup vs baseline: 1.1433x; 1.0295x over previous
//
#include <hip/hip_runtime.h>
#include <cstdint>

#define D_MODEL 128
#define D_EMB   64
#define MAXLEN  32
#define NB      2
#define NMSA    4
#define LL      768
#define JCHUNK  256   // j's per block (128KB contiguous stream per block)
#define NREL    (2 * MAXLEN - 1)

typedef float f32x4 __attribute__((ext_vector_type(4)));

// Fused prep:
//  blocks 0 .. NB*LL-1 : P[bi][d] = sum_k e[bi,k] * W_proj[k][d]
//                        Q[bi][d] = sum_k e[bi,k] * W_proj[64+k][d]
//  block  NB*LL        : R[r][d]  = W_pos[r][d] + b_pos[d] + b_proj[d]
__global__ void prep_kernel(const int* __restrict__ msa_tokens,
                            const float* __restrict__ emb,
                            const float* __restrict__ W_proj,
                            const float* __restrict__ b_proj,
                            const float* __restrict__ W_pos,
                            const float* __restrict__ b_pos,
                            float* __restrict__ P, float* __restrict__ Q,
                            float* __restrict__ R) {
    int bi = blockIdx.x;
    int d  = threadIdx.x;           // 0 .. 127
    if (bi == NB * LL) {
        float bias = b_pos[d] + b_proj[d];
        #pragma unroll
        for (int r = 0; r < NREL; ++r) {
            R[r * D_MODEL + d] = W_pos[r * D_MODEL + d] + bias;
        }
        return;
    }
    int b = bi / LL;
    int i = bi - b * LL;
    __shared__ float e[D_EMB];
    int tok = msa_tokens[(b * NMSA + 0) * LL + i];
    if (d < D_EMB) {
        e[d] = (tok != 0) ? emb[tok * D_EMB + d] : 0.0f;
    }
    __syncthreads();
    float p = 0.f, q = 0.f;
    #pragma unroll
    for (int k = 0; k < D_EMB; ++k) {
        float ek = e[k];
        p = fmaf(ek, W_proj[k * D_MODEL + d], p);
        q = fmaf(ek, W_proj[(D_EMB + k) * D_MODEL + d], q);
    }
    P[bi * D_MODEL + d] = p;
    Q[bi * D_MODEL + d] = q;
}

// out[b,i,j,d] = P[b,i,d] + Q[b,j,d] + R[clip(i-j,-31,31)+31, d]
// R10 structure (plain stores, 1 block/CU via 100KB ballast, 128KB stream
// per block) but 512 threads/block: same 256 concurrent write streams,
// DOUBLE the waves (8/CU) to hide Q/R load-hit latency in store issue.
__global__ __launch_bounds__(512) void fill_kernel(
        const float* __restrict__ P, const float* __restrict__ Q,
        const float* __restrict__ R, float* __restrict__ out) {
    volatile __shared__ float ballast[25600];   // 100 KB -> 1 block/CU
    ballast[threadIdx.x] = 0.0f;

    int bi    = blockIdx.y;         // b*LL + i
    int b     = bi / LL;
    int i     = bi - b * LL;
    int jbase = blockIdx.x * JCHUNK;
    int t     = threadIdx.x;
    int d4    = t & 31;             // which float4 of the 128-dim channel
    int jo    = t >> 5;             // 0..15

    const f32x4* P4 = reinterpret_cast<const f32x4*>(P);
    const f32x4* Qb = reinterpret_cast<const f32x4*>(Q + (size_t)b * LL * D_MODEL);
    const f32x4* R4 = reinterpret_cast<const f32x4*>(R);
    f32x4* orow = reinterpret_cast<f32x4*>(out + ((size_t)bi * LL + jbase) * D_MODEL);

    f32x4 p = P4[(size_t)bi * 32 + d4];

    #pragma unroll
    for (int jj = 0; jj < JCHUNK; jj += 16) {
        int j = jbase + jj + jo;
        int rel = i - j;
        rel = rel > (MAXLEN - 1) ? (MAXLEN - 1) : rel;
        rel = rel < -(MAXLEN - 1) ? -(MAXLEN - 1) : rel;
        rel += MAXLEN - 1;

        f32x4 q = Qb[(size_t)j * 32 + d4];
        f32x4 r = R4[rel * 32 + d4];
        orow[(size_t)(jj + jo) * 32 + d4] = p + q + r;
    }
}

extern "C" void kernel_launch(void* const* d_in, const int* in_sizes, int n_in,
                              void* d_out, int out_size, void* d_ws, size_t ws_size,
                              hipStream_t stream) {
    const int*   msa    = (const int*)d_in[0];
    const float* emb    = (const float*)d_in[1];
    const float* W_proj = (const float*)d_in[2];
    const float* b_proj = (const float*)d_in[3];
    const float* W_pos  = (const float*)d_in[4];
    const float* b_pos  = (const float*)d_in[5];
    float* out = (float*)d_out;

    float* P = (float*)d_ws;                       // NB*LL*128 floats
    float* Q = P + (size_t)NB * LL * D_MODEL;      // NB*LL*128 floats
    float* R = Q + (size_t)NB * LL * D_MODEL;      // NREL*128 floats

    prep_kernel<<<NB * LL + 1, D_MODEL, 0, stream>>>(msa, emb, W_proj, b_proj,
                                                     W_pos, b_pos, P, Q, R);
    fill_kernel<<<dim3(LL / JCHUNK, NB * LL), 512, 0, stream>>>(P, Q, R, out);
}

// Round 12
// 111.267 us; speedup vs baseline: 1.1607x; 1.0152x over previous
//
#include <hip/hip_runtime.h>
#include <cstdint>

#define D_MODEL 128
#define D_EMB   64
#define MAXLEN  32
#define NB      2
#define NMSA    4
#define LL      768
#define JCHUNK  256   // j's per block (128KB contiguous stream per block)
#define NREL    (2 * MAXLEN - 1)

typedef float f32x4 __attribute__((ext_vector_type(4)));

// Fused prep:
//  blocks 0 .. NB*LL-1 : P[bi][d] = sum_k e[bi,k] * W_proj[k][d]
//                        Q[bi][d] = sum_k e[bi,k] * W_proj[64+k][d]
//  block  NB*LL        : R[r][d]  = W_pos[r][d] + b_pos[d] + b_proj[d]
__global__ void prep_kernel(const int* __restrict__ msa_tokens,
                            const float* __restrict__ emb,
                            const float* __restrict__ W_proj,
                            const float* __restrict__ b_proj,
                            const float* __restrict__ W_pos,
                            const float* __restrict__ b_pos,
                            float* __restrict__ P, float* __restrict__ Q,
                            float* __restrict__ R) {
    int bi = blockIdx.x;
    int d  = threadIdx.x;           // 0 .. 127
    if (bi == NB * LL) {
        float bias = b_pos[d] + b_proj[d];
        #pragma unroll
        for (int r = 0; r < NREL; ++r) {
            R[r * D_MODEL + d] = W_pos[r * D_MODEL + d] + bias;
        }
        return;
    }
    int b = bi / LL;
    int i = bi - b * LL;
    __shared__ float e[D_EMB];
    int tok = msa_tokens[(b * NMSA + 0) * LL + i];
    if (d < D_EMB) {
        e[d] = (tok != 0) ? emb[tok * D_EMB + d] : 0.0f;
    }
    __syncthreads();
    float p = 0.f, q = 0.f;
    #pragma unroll
    for (int k = 0; k < D_EMB; ++k) {
        float ek = e[k];
        p = fmaf(ek, W_proj[k * D_MODEL + d], p);
        q = fmaf(ek, W_proj[(D_EMB + k) * D_MODEL + d], q);
    }
    P[bi * D_MODEL + d] = p;
    Q[bi * D_MODEL + d] = q;
}

// out[b,i,j,d] = P[b,i,d] + Q[b,j,d] + R[clip(i-j,-31,31)+31, d]
// R11 structure (plain stores, 1 block/CU via 100KB ballast, 128KB stream
// per block) but 1024 threads/block: same 256 concurrent write streams,
// 16 waves/CU to hide Q/R load-hit latency. Lever trend: 4w=116.3,
// 8w=113.0, this tests 16w.
__global__ __launch_bounds__(1024) void fill_kernel(
        const float* __restrict__ P, const float* __restrict__ Q,
        const float* __restrict__ R, float* __restrict__ out) {
    volatile __shared__ float ballast[25600];   // 100 KB -> 1 block/CU
    ballast[threadIdx.x] = 0.0f;

    int bi    = blockIdx.y;         // b*LL + i
    int b     = bi / LL;
    int i     = bi - b * LL;
    int jbase = blockIdx.x * JCHUNK;
    int t     = threadIdx.x;
    int d4    = t & 31;             // which float4 of the 128-dim channel
    int jo    = t >> 5;             // 0..31

    const f32x4* P4 = reinterpret_cast<const f32x4*>(P);
    const f32x4* Qb = reinterpret_cast<const f32x4*>(Q + (size_t)b * LL * D_MODEL);
    const f32x4* R4 = reinterpret_cast<const f32x4*>(R);
    f32x4* orow = reinterpret_cast<f32x4*>(out + ((size_t)bi * LL + jbase) * D_MODEL);

    f32x4 p = P4[(size_t)bi * 32 + d4];

    #pragma unroll
    for (int jj = 0; jj < JCHUNK; jj += 32) {
        int j = jbase + jj + jo;
        int rel = i - j;
        rel = rel > (MAXLEN - 1) ? (MAXLEN - 1) : rel;
        rel = rel < -(MAXLEN - 1) ? -(MAXLEN - 1) : rel;
        rel += MAXLEN - 1;

        f32x4 q = Qb[(size_t)j * 32 + d4];
        f32x4 r = R4[rel * 32 + d4];
        orow[(size_t)(jj + jo) * 32 + d4] = p + q + r;
    }
}

extern "C" void kernel_launch(void* const* d_in, const int* in_sizes, int n_in,
                              void* d_out, int out_size, void* d_ws, size_t ws_size,
                              hipStream_t stream) {
    const int*   msa    = (const int*)d_in[0];
    const float* emb    = (const float*)d_in[1];
    const float* W_proj = (const float*)d_in[2];
    const float* b_proj = (const float*)d_in[3];
    const float* W_pos  = (const float*)d_in[4];
    const float* b_pos  = (const float*)d_in[5];
    float* out = (float*)d_out;

    float* P = (float*)d_ws;                       // NB*LL*128 floats
    float* Q = P + (size_t)NB * LL * D_MODEL;      // NB*LL*128 floats
    float* R = Q + (size_t)NB * LL * D_MODEL;      // NREL*128 floats

    prep_kernel<<<NB * LL + 1, D_MODEL, 0, stream>>>(msa, emb, W_proj, b_proj,
                                                     W_pos, b_pos, P, Q, R);
    fill_kernel<<<dim3(LL / JCHUNK, NB * LL), 1024, 0, stream>>>(P, Q, R, out);
}

// Round 13
// 108.314 us; speedup vs baseline: 1.1924x; 1.0273x over previous
//
#include <hip/hip_runtime.h>
#include <cstdint>

#define D_MODEL 128
#define D_EMB   64
#define MAXLEN  32
#define NB      2
#define NMSA    4
#define LL      768
#define JCHUNK  256   // j's per block (128KB contiguous stream per block)
#define NREL    (2 * MAXLEN - 1)

typedef float f32x4 __attribute__((ext_vector_type(4)));

// Fused prep:
//  blocks 0 .. NB*LL-1 : P[bi][d] = sum_k e[bi,k] * W_proj[k][d]
//                        Q[bi][d] = sum_k e[bi,k] * W_proj[64+k][d]
//  block  NB*LL        : R[r][d]  = W_pos[r][d] + b_pos[d] + b_proj[d]
__global__ void prep_kernel(const int* __restrict__ msa_tokens,
                            const float* __restrict__ emb,
                            const float* __restrict__ W_proj,
                            const float* __restrict__ b_proj,
                            const float* __restrict__ W_pos,
                            const float* __restrict__ b_pos,
                            float* __restrict__ P, float* __restrict__ Q,
                            float* __restrict__ R) {
    int bi = blockIdx.x;
    int d  = threadIdx.x;           // 0 .. 127
    if (bi == NB * LL) {
        float bias = b_pos[d] + b_proj[d];
        #pragma unroll
        for (int r = 0; r < NREL; ++r) {
            R[r * D_MODEL + d] = W_pos[r * D_MODEL + d] + bias;
        }
        return;
    }
    int b = bi / LL;
    int i = bi - b * LL;
    __shared__ float e[D_EMB];
    int tok = msa_tokens[(b * NMSA + 0) * LL + i];
    if (d < D_EMB) {
        e[d] = (tok != 0) ? emb[tok * D_EMB + d] : 0.0f;
    }
    __syncthreads();
    float p = 0.f, q = 0.f;
    #pragma unroll
    for (int k = 0; k < D_EMB; ++k) {
        float ek = e[k];
        p = fmaf(ek, W_proj[k * D_MODEL + d], p);
        q = fmaf(ek, W_proj[(D_EMB + k) * D_MODEL + d], q);
    }
    P[bi * D_MODEL + d] = p;
    Q[bi * D_MODEL + d] = q;
}

// out[b,i,j,d] = P[b,i,d] + Q[b,j,d] + R[clip(i-j,-31,31)+31, d]
// R12 structure (plain stores, 1 block/CU via 100KB ballast, 1024 thr,
// 128KB stream per block). New: rel-saturation fold — when the whole
// j-chunk is >=31 off-diagonal (rel const: ~2/3 of blocks), fold R into
// the hoisted P; inner loop becomes load-Q/add/store (halves load issue).
__global__ __launch_bounds__(1024) void fill_kernel(
        const float* __restrict__ P, const float* __restrict__ Q,
        const float* __restrict__ R, float* __restrict__ out) {
    volatile __shared__ float ballast[25600];   // 100 KB -> 1 block/CU
    ballast[threadIdx.x] = 0.0f;

    int bi    = blockIdx.y;         // b*LL + i
    int b     = bi / LL;
    int i     = bi - b * LL;
    int jbase = blockIdx.x * JCHUNK;
    int t     = threadIdx.x;
    int d4    = t & 31;             // which float4 of the 128-dim channel
    int jo    = t >> 5;             // 0..31

    const f32x4* P4 = reinterpret_cast<const f32x4*>(P);
    const f32x4* Qb = reinterpret_cast<const f32x4*>(Q + (size_t)b * LL * D_MODEL);
    const f32x4* R4 = reinterpret_cast<const f32x4*>(R);
    f32x4* orow = reinterpret_cast<f32x4*>(out + ((size_t)bi * LL + jbase) * D_MODEL);

    f32x4 p = P4[(size_t)bi * 32 + d4];

    bool sat_lo = (jbase >= i + (MAXLEN - 1));               // all rel = 0
    bool sat_hi = (jbase + JCHUNK - 1 <= i - (MAXLEN - 1));  // all rel = 62

    if (sat_lo || sat_hi) {
        f32x4 pr = p + R4[(sat_lo ? 0 : (NREL - 1)) * 32 + d4];
        #pragma unroll
        for (int jj = 0; jj < JCHUNK; jj += 32) {
            int j = jbase + jj + jo;
            f32x4 q = Qb[(size_t)j * 32 + d4];
            orow[(size_t)(jj + jo) * 32 + d4] = pr + q;
        }
    } else {
        #pragma unroll
        for (int jj = 0; jj < JCHUNK; jj += 32) {
            int j = jbase + jj + jo;
            int rel = i - j;
            rel = rel > (MAXLEN - 1) ? (MAXLEN - 1) : rel;
            rel = rel < -(MAXLEN - 1) ? -(MAXLEN - 1) : rel;
            rel += MAXLEN - 1;

            f32x4 q = Qb[(size_t)j * 32 + d4];
            f32x4 r = R4[rel * 32 + d4];
            orow[(size_t)(jj + jo) * 32 + d4] = p + q + r;
        }
    }
}

extern "C" void kernel_launch(void* const* d_in, const int* in_sizes, int n_in,
                              void* d_out, int out_size, void* d_ws, size_t ws_size,
                              hipStream_t stream) {
    const int*   msa    = (const int*)d_in[0];
    const float* emb    = (const float*)d_in[1];
    const float* W_proj = (const float*)d_in[2];
    const float* b_proj = (const float*)d_in[3];
    const float* W_pos  = (const float*)d_in[4];
    const float* b_pos  = (const float*)d_in[5];
    float* out = (float*)d_out;

    float* P = (float*)d_ws;                       // NB*LL*128 floats
    float* Q = P + (size_t)NB * LL * D_MODEL;      // NB*LL*128 floats
    float* R = Q + (size_t)NB * LL * D_MODEL;      // NREL*128 floats

    prep_kernel<<<NB * LL + 1, D_MODEL, 0, stream>>>(msa, emb, W_proj, b_proj,
                                                     W_pos, b_pos, P, Q, R);
    fill_kernel<<<dim3(LL / JCHUNK, NB * LL), 1024, 0, stream>>>(P, Q, R, out);
}